// Round 2
// baseline (41.168 us; speedup 1.0000x reference)
//
#include <hip/hip_runtime.h>

typedef __attribute__((ext_vector_type(8))) short bf16x8;
typedef __attribute__((ext_vector_type(4))) float f32x4;

__device__ __forceinline__ unsigned short f2bf(float f){
  union { float f; unsigned int u; } v; v.f = f;
  unsigned int u = v.u;
  return (unsigned short)((u + 0x7FFFu + ((u >> 16) & 1u)) >> 16);  // RNE
}

__device__ __forceinline__ float fast_tanh(float x){
  x = fminf(15.f, fmaxf(-15.f, x));
  float e = __expf(2.f * x);
  return (e - 1.f) / (e + 1.f);
}

// ---------------------------------------------------------------------------
// K0: precompute small tables into ws (floats):
//   [0..1024)    MT[g*32+h] = M[h][g] = sum_c Wk2[h][c]*Wq2[g][c]
//   [1024..1056) u[h]  = sum_c Wk2[h][c]*bq2[c]
//   [1056..1088) r[g]  = sum_c Wq2[g][c]*bk2[c]
//   [1088..1120) wv[h] = sum_c Wv2[h][c]*Wval[c]
//   [1120]       cc = bk2.bq2      [1121] cv = bv2.Wval1
//   ws+1152: Bpack (12288 bf16): layer-1 weights in MFMA B-frag order
// ---------------------------------------------------------------------------
__global__ __launch_bounds__(64) void k0_kernel(
    const float* __restrict__ Wk1, const float* __restrict__ Wq1, const float* __restrict__ Wv1,
    const float* __restrict__ Wk2, const float* __restrict__ bk2,
    const float* __restrict__ Wq2, const float* __restrict__ bq2,
    const float* __restrict__ Wv2, const float* __restrict__ bv2,
    const float* __restrict__ Wval, float* __restrict__ ws)
{
  const int tid = blockIdx.x * 64 + threadIdx.x;  // 0..4095
  if (tid < 1024){
    const int g = tid >> 5, h = tid & 31;
    const float* wk = Wk2 + h * 128;
    const float* wq = Wq2 + g * 128;
    float s = 0.f;
    for (int c = 0; c < 128; c += 4){
      float4 a = *(const float4*)(wk + c);
      float4 bqv = *(const float4*)(wq + c);
      s += a.x*bqv.x + a.y*bqv.y + a.z*bqv.z + a.w*bqv.w;
    }
    ws[tid] = s;                       // MT[g*32+h]
  } else if (tid < 1120){
    const int h = tid - 1024; const int m = h >> 5; const int hh = h & 31;
    const float* W2  = (m == 0) ? Wk2 : ((m == 1) ? Wq2 : Wv2);
    const float* vec = (m == 0) ? bq2 : ((m == 1) ? bk2 : Wval);
    float s = 0.f;
    for (int c = 0; c < 128; c++) s += W2[hh * 128 + c] * vec[c];
    ws[1024 + m * 32 + hh] = s;
  } else if (tid == 1120){
    float s = 0.f; for (int c = 0; c < 128; c++) s += bk2[c] * bq2[c];
    ws[1120] = s;
  } else if (tid == 1121){
    float s = 0.f; for (int c = 0; c < 128; c++) s += bv2[c] * Wval[c];
    ws[1121] = s;
  }
  unsigned short* bp = (unsigned short*)(ws + 1152);
  for (int idx = tid; idx < 12288; idx += 4096){
    const int e  = idx & 7;
    const int l  = (idx >> 3) & 63;
    const int kc = (idx >> 9) & 3;
    const int nt = (idx >> 11) & 1;
    const int m  = idx >> 12;
    const float* W1 = (m == 0) ? Wk1 : ((m == 1) ? Wq1 : Wv1);
    const int krow = kc * 32 + (l >> 4) * 8 + e;
    const int col  = nt * 16 + (l & 15);
    bp[idx] = f2bf(W1[krow * 32 + col]);
  }
}

// ---------------------------------------------------------------------------
// Fused kernel: one wave = one batch, end to end.
//   attention (MFMA layer-1 + fp32 score path + softmax) -> alpha, ov
//   noise/PRD streaming (two 16x float4 register chunks) -> nv
//   final combine -> x
// After the single table barrier, every wave is independent: no further
// __syncthreads, so waves desync and memory latency hides under VALU loops.
// ---------------------------------------------------------------------------
#define HSTR 20

#define ROWSOFTMAX(sv, aout) { \
    float m_ = sv; \
    m_ = fmaxf(m_, __shfl_xor(m_, 1)); m_ = fmaxf(m_, __shfl_xor(m_, 2)); \
    m_ = fmaxf(m_, __shfl_xor(m_, 4)); m_ = fmaxf(m_, __shfl_xor(m_, 8)); \
    float p_ = __expf(sv - m_); \
    float su_ = p_; \
    su_ += __shfl_xor(su_, 1); su_ += __shfl_xor(su_, 2); \
    su_ += __shfl_xor(su_, 4); su_ += __shfl_xor(su_, 8); \
    aout = p_ / su_; }

#define GRPSUM(x) { x += __shfl_xor(x, 1); x += __shfl_xor(x, 2); \
                    x += __shfl_xor(x, 4); x += __shfl_xor(x, 8); }

__global__ __launch_bounds__(256, 2) void fused_kernel(
    const float* __restrict__ obs,
    const float* __restrict__ policies, const float* __restrict__ actions,
    const float* __restrict__ noise, const float* __restrict__ weights,
    const float* __restrict__ bk1, const float* __restrict__ bq1, const float* __restrict__ bv1,
    const float* __restrict__ Wval, const float* __restrict__ bval,
    const float* __restrict__ ws,
    float* __restrict__ out_x, float* __restrict__ out_alpha)
{
  __shared__ __align__(16) float MT[32 * 36];
  __shared__ __align__(16) float ul[32], rl[32], wvl[32], ccl[2];
  __shared__ __align__(16) float hT[4][96 * HSTR];
  __shared__ __align__(16) float tqT[4][32 * HSTR];
  __shared__ __align__(16) float rql[4][16];
  __shared__ __align__(16) float nvl[4][256];
  __shared__ __align__(16) float pvl[4][16], avl[4][16], ovl[4][16];

  const int t = threadIdx.x;
  const int wid = t >> 6, lane = t & 63;
  const int b = blockIdx.x * 4 + wid;
  const int jl = lane & 15;   // node/sender slot within 16-group
  const int gq = lane >> 4;   // 16-lane group id 0..3
  float* hTl  = hT[wid];
  float* tqTl = tqT[wid];
  float* nvw  = nvl[wid];

  // ---- table load (only barrier in the kernel)
  for (int idx = t; idx < 1024; idx += 256) MT[(idx >> 5) * 36 + (idx & 31)] = ws[idx];
  if (t < 32){ ul[t] = ws[1024 + t]; rl[t] = ws[1056 + t]; wvl[t] = ws[1088 + t]; }
  if (t < 2) ccl[t] = ws[1120 + t];
  __syncthreads();

  // ---- issue per-wave global loads (obs, pol/act, noise chunk A)
  const float* orow = obs + ((size_t)(b * 16 + jl)) * 128 + gq * 8;
  float4 ob[8];
#pragma unroll
  for (int kc = 0; kc < 4; kc++){
    ob[kc * 2]     = *(const float4*)(orow + kc * 32);
    ob[kc * 2 + 1] = *(const float4*)(orow + kc * 32 + 4);
  }
  const int jp = lane >> 2, seg = lane & 3;
  const float* pp = policies + ((size_t)(b * 16 + jp)) * 32 + seg * 8;
  const float* ap = actions  + ((size_t)(b * 16 + jp)) * 32 + seg * 8;
  float4 pA0 = *(const float4*)(pp);
  float4 pA1 = *(const float4*)(pp + 4);
  float4 aA0 = *(const float4*)(ap);
  float4 aA1 = *(const float4*)(ap + 4);
  const float4 wpa = *(const float4*)(Wval + 128 + seg * 8);
  const float4 wpb = *(const float4*)(Wval + 132 + seg * 8);
  const int q8 = lane & 7;
  const float4 wv4 = *(const float4*)(Wval + 128 + q8 * 4);
  const float* nb = noise + (size_t)b * 8192 + (lane >> 3) * 32 + q8 * 4;
  float4 nzA[16];
#pragma unroll
  for (int p = 0; p < 16; p++) nzA[p] = *(const float4*)(nb + p * 256);
  const float wscal = weights[0];
  const float bv0 = bval[0];

  // ---- pv/av: 4 lanes per node jp, 8 dims each, reduce over seg
  {
    float pvv = pA0.x*wpa.x + pA0.y*wpa.y + pA0.z*wpa.z + pA0.w*wpa.w
              + pA1.x*wpb.x + pA1.y*wpb.y + pA1.z*wpb.z + pA1.w*wpb.w;
    float avv = aA0.x*wpa.x + aA0.y*wpa.y + aA0.z*wpa.z + aA0.w*wpa.w
              + aA1.x*wpb.x + aA1.y*wpb.y + aA1.z*wpb.z + aA1.w*wpb.w;
    pvv += __shfl_xor(pvv, 1); pvv += __shfl_xor(pvv, 2);
    avv += __shfl_xor(avv, 1); avv += __shfl_xor(avv, 2);
    if (seg == 0){ pvl[wid][jp] = pvv; avl[wid][jp] = avv; }
  }

  // ---- A fragments + MFMA layer-1 + tanh -> hT
  bf16x8 afr[4];
#pragma unroll
  for (int kc = 0; kc < 4; kc++){
    bf16x8 a;
    a[0] = (short)f2bf(ob[kc*2].x); a[1] = (short)f2bf(ob[kc*2].y);
    a[2] = (short)f2bf(ob[kc*2].z); a[3] = (short)f2bf(ob[kc*2].w);
    a[4] = (short)f2bf(ob[kc*2+1].x); a[5] = (short)f2bf(ob[kc*2+1].y);
    a[6] = (short)f2bf(ob[kc*2+1].z); a[7] = (short)f2bf(ob[kc*2+1].w);
    afr[kc] = a;
  }
  const bf16x8* bp = (const bf16x8*)(ws + 1152);
#pragma unroll
  for (int mt = 0; mt < 6; mt++){
    f32x4 c = {0.f, 0.f, 0.f, 0.f};
#pragma unroll
    for (int kc = 0; kc < 4; kc++){
      bf16x8 bfr = bp[(mt * 4 + kc) * 64 + lane];
      c = __builtin_amdgcn_mfma_f32_16x16x32_bf16(afr[kc], bfr, c, 0, 0, 0);
    }
    const int m = mt >> 1;
    const int hcol = ((mt & 1) << 4) + jl;
    const float* bb = (m == 0) ? bk1 : ((m == 1) ? bq1 : bv1);
    const float bias = bb[hcol];
    float4 hv;
    hv.x = fast_tanh(c[0] + bias);
    hv.y = fast_tanh(c[1] + bias);
    hv.z = fast_tanh(c[2] + bias);
    hv.w = fast_tanh(c[3] + bias);
    *(float4*)(&hTl[(m * 32 + hcol) * HSTR + gq * 4]) = hv;
  }

  // ---- consume noise chunk A (rows 0..127), then issue chunk B
#pragma unroll
  for (int p = 0; p < 16; p++){
    float s = nzA[p].x*wv4.x + nzA[p].y*wv4.y + nzA[p].z*wv4.z + nzA[p].w*wv4.w;
    s += __shfl_xor(s, 1); s += __shfl_xor(s, 2); s += __shfl_xor(s, 4);
    if (q8 == 0) nvw[p * 8 + (lane >> 3)] = s;
  }
  float4 nzB[16];
#pragma unroll
  for (int p = 0; p < 16; p++) nzB[p] = *(const float4*)(nb + 4096 + p * 256);

  // ---- vv[j] = h_v[j,:].wv + cv  (j = jl; redundant across gq groups)
  float vv = ccl[1];
#pragma unroll 8
  for (int h = 0; h < 32; h++) vv += wvl[h] * hTl[(64 + h) * HSTR + jl];

  // ---- tq[i][h] = sum_g M[h][g] hq[i][g];  rq[i] = sum_g r[g] hq[i][g]; i = jl
  float tq0=0,tq1=0,tq2=0,tq3=0,tq4=0,tq5=0,tq6=0,tq7=0, rqv=0;
  const int h8 = gq * 8;
  for (int g = 0; g < 32; g++){
    const float hq = hTl[(32 + g) * HSTR + jl];
    float4 m0 = *(const float4*)(&MT[g * 36 + h8]);
    float4 m1 = *(const float4*)(&MT[g * 36 + h8 + 4]);
    tq0 += m0.x * hq; tq1 += m0.y * hq; tq2 += m0.z * hq; tq3 += m0.w * hq;
    tq4 += m1.x * hq; tq5 += m1.y * hq; tq6 += m1.z * hq; tq7 += m1.w * hq;
    rqv += rl[g] * hq;
  }
  tqTl[(h8 + 0) * HSTR + jl] = tq0;
  tqTl[(h8 + 1) * HSTR + jl] = tq1;
  tqTl[(h8 + 2) * HSTR + jl] = tq2;
  tqTl[(h8 + 3) * HSTR + jl] = tq3;
  tqTl[(h8 + 4) * HSTR + jl] = tq4;
  tqTl[(h8 + 5) * HSTR + jl] = tq5;
  tqTl[(h8 + 6) * HSTR + jl] = tq6;
  tqTl[(h8 + 7) * HSTR + jl] = tq7;
  if (gq == 0) rql[wid][jl] = rqv;

  // ---- scores[i][j]: j = jl, i = 4*gq + r
  float sc0=0,sc1=0,sc2=0,sc3=0, uk=0;
  for (int h = 0; h < 32; h++){
    const float hk = hTl[h * HSTR + jl];
    float4 tqv = *(const float4*)(&tqTl[h * HSTR + gq * 4]);
    sc0 += hk * tqv.x; sc1 += hk * tqv.y; sc2 += hk * tqv.z; sc3 += hk * tqv.w;
    uk += ul[h] * hk;
  }
  const float cc = ccl[0];
  const float rs = 0.08838834764831845f;  // 1/sqrt(128)
  float s0 = (sc0 + uk + rql[wid][gq * 4 + 0] + cc) * rs;
  float s1 = (sc1 + uk + rql[wid][gq * 4 + 1] + cc) * rs;
  float s2 = (sc2 + uk + rql[wid][gq * 4 + 2] + cc) * rs;
  float s3 = (sc3 + uk + rql[wid][gq * 4 + 3] + cc) * rs;

  // ---- softmax over j (lanes within 16-group)
  float a0, a1, a2, a3;
  ROWSOFTMAX(s0, a0); ROWSOFTMAX(s1, a1); ROWSOFTMAX(s2, a2); ROWSOFTMAX(s3, a3);

  float* oa = out_alpha + (size_t)b * 256;
  oa[gq * 64 +  0 + jl] = a0;
  oa[gq * 64 + 16 + jl] = a1;
  oa[gq * 64 + 32 + jl] = a2;
  oa[gq * 64 + 48 + jl] = a3;

  // ---- ov[i] = sum_j alpha[i][j] * vv[j]  -> LDS
  float o0 = a0 * vv; GRPSUM(o0);
  float o1 = a1 * vv; GRPSUM(o1);
  float o2 = a2 * vv; GRPSUM(o2);
  float o3 = a3 * vv; GRPSUM(o3);
  if (jl == 0) ovl[wid][gq * 4 + 0] = o0;
  if (jl == 1) ovl[wid][gq * 4 + 1] = o1;
  if (jl == 2) ovl[wid][gq * 4 + 2] = o2;
  if (jl == 3) ovl[wid][gq * 4 + 3] = o3;

  // ---- consume noise chunk B (rows 128..255)
#pragma unroll
  for (int p = 0; p < 16; p++){
    float s = nzB[p].x*wv4.x + nzB[p].y*wv4.y + nzB[p].z*wv4.z + nzB[p].w*wv4.w;
    s += __shfl_xor(s, 1); s += __shfl_xor(s, 2); s += __shfl_xor(s, 4);
    if (q8 == 0) nvw[128 + p * 8 + (lane >> 3)] = s;
  }

  // ---- final combine: lane covers 4 consecutive outputs (fixed i)
  {
    const int j0 = (lane & 3) * 4;       // sender block
    const int ii = lane >> 2;            // receiver
    float4 pv4 = *(const float4*)(&pvl[wid][j0]);
    float4 av4 = *(const float4*)(&avl[wid][j0]);
    float4 ov4 = *(const float4*)(&ovl[wid][j0]);
    float4 nv4 = *(const float4*)(&nvw[ii * 16 + j0]);
    const float om = 1.f - wscal;
    float z0 = wscal * av4.x + om * pv4.x + nv4.x;
    float z1 = wscal * av4.y + om * pv4.y + nv4.y;
    float z2 = wscal * av4.z + om * pv4.z + nv4.z;
    float z3 = wscal * av4.w + om * pv4.w + nv4.w;
    float zs = z0 + z1 + z2 + z3;
    zs += __shfl_xor(zs, 1); zs += __shfl_xor(zs, 2);  // sum over 16 senders
    float4 o;
    o.x = ov4.x + (pv4.x - z0 + zs) * 0.0625f + bv0;
    o.y = ov4.y + (pv4.y - z1 + zs) * 0.0625f + bv0;
    o.z = ov4.z + (pv4.z - z2 + zs) * 0.0625f + bv0;
    o.w = ov4.w + (pv4.w - z3 + zs) * 0.0625f + bv0;
    *(float4*)(out_x + (size_t)b * 256 + lane * 4) = o;
  }
}

// ---------------------------------------------------------------------------
extern "C" void kernel_launch(void* const* d_in, const int* in_sizes, int n_in,
                              void* d_out, int out_size, void* d_ws, size_t ws_size,
                              hipStream_t stream)
{
  const float* obs      = (const float*)d_in[0];
  const float* policies = (const float*)d_in[1];
  const float* actions  = (const float*)d_in[2];
  const float* weights  = (const float*)d_in[3];
  const float* noise    = (const float*)d_in[4];
  const float* Wk1  = (const float*)d_in[5];
  const float* bk1  = (const float*)d_in[6];
  const float* Wk2  = (const float*)d_in[7];
  const float* bk2  = (const float*)d_in[8];
  const float* Wq1  = (const float*)d_in[9];
  const float* bq1  = (const float*)d_in[10];
  const float* Wq2  = (const float*)d_in[11];
  const float* bq2  = (const float*)d_in[12];
  const float* Wv1  = (const float*)d_in[13];
  const float* bv1  = (const float*)d_in[14];
  const float* Wv2  = (const float*)d_in[15];
  const float* bv2  = (const float*)d_in[16];
  const float* Wval = (const float*)d_in[17];
  const float* bval = (const float*)d_in[18];

  float* out = (float*)d_out;
  float* ws  = (float*)d_ws;

  const int NODES = in_sizes[0] / 128;
  const int B = NODES / 16;

  hipLaunchKernelGGL(k0_kernel, dim3(64), dim3(64), 0, stream,
                     Wk1, Wq1, Wv1, Wk2, bk2, Wq2, bq2, Wv2, bv2, Wval, ws);
  hipLaunchKernelGGL(fused_kernel, dim3(B / 4), dim3(256), 0, stream,
                     obs, policies, actions, noise, weights,
                     bk1, bq1, bv1, Wval, bval, ws,
                     out, out + (size_t)NODES * 16);
}

// Round 3
// 31.358 us; speedup vs baseline: 1.3129x; 1.3129x over previous
//
#include <hip/hip_runtime.h>

typedef __attribute__((ext_vector_type(8))) short bf16x8;
typedef __attribute__((ext_vector_type(4))) float f32x4;

__device__ __forceinline__ unsigned short f2bf(float f){
  union { float f; unsigned int u; } v; v.f = f;
  unsigned int u = v.u;
  return (unsigned short)((u + 0x7FFFu + ((u >> 16) & 1u)) >> 16);  // RNE
}

__device__ __forceinline__ float fast_tanh(float x){
  x = fminf(15.f, fmaxf(-15.f, x));
  float e = __expf(2.f * x);
  return (e - 1.f) / (e + 1.f);
}

__device__ __forceinline__ float dot128(const float* __restrict__ a,
                                        const float* __restrict__ b){
  float s = 0.f;
  for (int c = 0; c < 128; c += 4){
    float4 x = *(const float4*)(a + c);
    float4 y = *(const float4*)(b + c);
    s += x.x*y.x + x.y*y.y + x.z*y.z + x.w*y.w;
  }
  return s;
}

#define GRPSUM(x) { x += __shfl_xor(x, 1); x += __shfl_xor(x, 2); \
                    x += __shfl_xor(x, 4); x += __shfl_xor(x, 8); }

// ---------------------------------------------------------------------------
// ws float layout:
//   f[0 .. 6144)    : Bpack   — MFMA1 B-frags (12288 bf16), layer-1 weights
//   f[6144 .. 6912) : B2pack  — MFMA2' B-frags (1536 bf16): 3 tiles
//                      tile0/1: B[k=g][n=h] = rs*M[h][g];  tile2 col0 = rs*r[g]
//   f[6912 .. 6944) : u'[h] = rs * (Wk2[h] . bq2)
//   f[6944 .. 6976) : wv[h] = Wv2[h] . Wval[0:128]
//   f[6976] = rs*(bk2.bq2)   f[6977] = bv2 . Wval[0:128]
//   f[7168 .. 7168+B*16) : ws_ov
// ---------------------------------------------------------------------------
__global__ __launch_bounds__(64) void k0_kernel(
    const float* __restrict__ Wk1, const float* __restrict__ Wq1, const float* __restrict__ Wv1,
    const float* __restrict__ Wk2, const float* __restrict__ bk2,
    const float* __restrict__ Wq2, const float* __restrict__ bq2,
    const float* __restrict__ Wv2, const float* __restrict__ bv2,
    const float* __restrict__ Wval, float* __restrict__ ws)
{
  const int tid = blockIdx.x * 64 + threadIdx.x;  // 0..4095
  const float rs = 0.08838834764831845f;          // 1/sqrt(128)
  unsigned short* bp = (unsigned short*)ws;
  unsigned short* b2 = (unsigned short*)(ws + 6144);

  if (tid < 1536){
    const int e = tid & 7, l = (tid >> 3) & 63, tt = tid >> 9;
    const int g = (l >> 4) * 8 + e;
    float val = 0.f;
    if (tt < 2){
      const int h = (l & 15) + tt * 16;
      val = rs * dot128(Wk2 + h * 128, Wq2 + g * 128);
    } else if ((l & 15) == 0){
      val = rs * dot128(Wq2 + g * 128, bk2);
    }
    b2[tid] = f2bf(val);
  } else if (tid < 1600){
    const int h = tid - 1536;
    if (h < 32) ws[6912 + h] = rs * dot128(Wk2 + h * 128, bq2);
    else        ws[6944 + (h - 32)] = dot128(Wv2 + (h - 32) * 128, Wval);
  } else if (tid == 1600){
    ws[6976] = rs * dot128(bk2, bq2);
  } else if (tid == 1601){
    ws[6977] = dot128(bv2, Wval);
  }

  for (int idx = tid; idx < 12288; idx += 4096){
    const int e  = idx & 7;
    const int l  = (idx >> 3) & 63;
    const int kc = (idx >> 9) & 3;
    const int nt = (idx >> 11) & 1;
    const int m  = idx >> 12;
    const float* W1 = (m == 0) ? Wk1 : ((m == 1) ? Wq1 : Wv1);
    const int krow = kc * 32 + (l >> 4) * 8 + e;
    const int col  = nt * 16 + (l & 15);
    bp[idx] = f2bf(W1[krow * 32 + col]);
  }
}

// ---------------------------------------------------------------------------
// K1: block-specialized.
//   blocks [0, BA)      : attention, 4 waves x 1 batch (MFMA score path)
//   blocks [BA, BA+B)   : noise streaming -> nv staged into out_x
// ---------------------------------------------------------------------------
__global__ __launch_bounds__(256) void k1_kernel(
    const float* __restrict__ obs, const float* __restrict__ noise,
    const float* __restrict__ bk1p, const float* __restrict__ bq1p, const float* __restrict__ bv1p,
    const float* __restrict__ Wval, const float* __restrict__ ws,
    float* __restrict__ out_x, float* __restrict__ out_alpha,
    float* __restrict__ ws_ov, int BA)
{
  __shared__ __align__(16) unsigned short hk_s[4][512];
  __shared__ __align__(16) unsigned short hq_s[4][512];
  __shared__ __align__(16) unsigned short tq_s[4][512];
  __shared__ __align__(16) float rql_s[4][16];
  __shared__ __align__(16) float vvl_s[4][16];
  __shared__ float nvw[256];

  const int t = threadIdx.x;

  if ((int)blockIdx.x >= BA){
    // ---------------- noise path ----------------
    const int b = blockIdx.x - BA;
    const int q = t & 7;
    const float4 wv4 = *(const float4*)(Wval + 128 + q * 4);
    const float* nb = noise + (size_t)b * 8192 + (t >> 3) * 32 + q * 4;
#pragma unroll
    for (int p = 0; p < 8; p++){
      float4 n4 = *(const float4*)(nb + p * 1024);
      float s = n4.x*wv4.x + n4.y*wv4.y + n4.z*wv4.z + n4.w*wv4.w;
      s += __shfl_xor(s, 1); s += __shfl_xor(s, 2); s += __shfl_xor(s, 4);
      if (q == 0) nvw[p * 32 + (t >> 3)] = s;
    }
    __syncthreads();
    out_x[(size_t)b * 256 + t] = nvw[t];
    return;
  }

  // ---------------- attention path ----------------
  const int wid = t >> 6, l = t & 63;
  const int b = blockIdx.x * 4 + wid;
  const int li = l & 15, gp = l >> 4;

  // prefetch obs rows -> A frags
  const float* orow = obs + (size_t)(b * 16 + li) * 128 + gp * 8;
  bf16x8 afr[4];
#pragma unroll
  for (int kc = 0; kc < 4; kc++){
    float4 x0 = *(const float4*)(orow + kc * 32);
    float4 x1 = *(const float4*)(orow + kc * 32 + 4);
    bf16x8 a;
    a[0]=(short)f2bf(x0.x); a[1]=(short)f2bf(x0.y); a[2]=(short)f2bf(x0.z); a[3]=(short)f2bf(x0.w);
    a[4]=(short)f2bf(x1.x); a[5]=(short)f2bf(x1.y); a[6]=(short)f2bf(x1.z); a[7]=(short)f2bf(x1.w);
    afr[kc] = a;
  }
  const bf16x8* bp  = (const bf16x8*)ws;
  const bf16x8* b2p = (const bf16x8*)(ws + 6144);
  const bf16x8 b20 = b2p[l], b21 = b2p[64 + l], b22 = b2p[128 + l];
  const float u0 = ws[6912 + li], u1 = ws[6928 + li];
  const float wv0 = ws[6944 + li], wv1 = ws[6960 + li];
  const float ccv = ws[6976], cvv = ws[6977];
  const float bk0 = bk1p[li], bk1v = bk1p[16 + li];
  const float bq0 = bq1p[li], bq1v = bq1p[16 + li];
  const float bv0 = bv1p[li], bv1v = bv1p[16 + li];

  // MFMA1: h = obs @ W1 for k,q,v (6 tiles x K=128)
  f32x4 acc[6];
#pragma unroll
  for (int mt = 0; mt < 6; mt++){ f32x4 z = {0.f,0.f,0.f,0.f}; acc[mt] = z; }
#pragma unroll
  for (int mt = 0; mt < 6; mt++){
#pragma unroll
    for (int kc = 0; kc < 4; kc++)
      acc[mt] = __builtin_amdgcn_mfma_f32_16x16x32_bf16(afr[kc], bp[(mt*4+kc)*64 + l], acc[mt], 0, 0, 0);
  }

  // tanh + pack hk, hq into [node][h] bf16 LDS images
  unsigned short* hkb = hk_s[wid];
  unsigned short* hqb = hq_s[wid];
#pragma unroll
  for (int tile = 0; tile < 2; tile++){
    const float bk_ = tile ? bk1v : bk0;
    const float bq_ = tile ? bq1v : bq0;
    f32x4 ck = acc[tile], cq = acc[2 + tile];
#pragma unroll
    for (int r = 0; r < 4; r++){
      hkb[(gp*4+r)*32 + tile*16 + li] = f2bf(fast_tanh(ck[r] + bk_));
      hqb[(gp*4+r)*32 + tile*16 + li] = f2bf(fast_tanh(cq[r] + bq_));
    }
  }

  // vv[j] = wv . tanh(h_v[j]) + cv   (shfl reduce over h lanes)
  {
    f32x4 c0 = acc[4], c1 = acc[5];
    float vp0 = wv0*fast_tanh(c0[0]+bv0) + wv1*fast_tanh(c1[0]+bv1v);
    float vp1 = wv0*fast_tanh(c0[1]+bv0) + wv1*fast_tanh(c1[1]+bv1v);
    float vp2 = wv0*fast_tanh(c0[2]+bv0) + wv1*fast_tanh(c1[2]+bv1v);
    float vp3 = wv0*fast_tanh(c0[3]+bv0) + wv1*fast_tanh(c1[3]+bv1v);
    GRPSUM(vp0); GRPSUM(vp1); GRPSUM(vp2); GRPSUM(vp3);
    if (li == 0){
      float4 vq; vq.x = vp0+cvv; vq.y = vp1+cvv; vq.z = vp2+cvv; vq.w = vp3+cvv;
      *(float4*)&vvl_s[wid][gp*4] = vq;
    }
  }

  // MFMA2': tq[i][h] = hq[i] . (rs*M^T)[.,h] + rs*u[h];  tile2 -> rs*(rq[i]+cc)
  const bf16x8 aq = *(const bf16x8*)(hqb + li*32 + gp*8);
  f32x4 cu0 = {u0,u0,u0,u0}, cu1 = {u1,u1,u1,u1}, cu2 = {ccv,ccv,ccv,ccv};
  f32x4 tq0 = __builtin_amdgcn_mfma_f32_16x16x32_bf16(aq, b20, cu0, 0, 0, 0);
  f32x4 tq1 = __builtin_amdgcn_mfma_f32_16x16x32_bf16(aq, b21, cu1, 0, 0, 0);
  f32x4 rqt = __builtin_amdgcn_mfma_f32_16x16x32_bf16(aq, b22, cu2, 0, 0, 0);
  if (li == 0){
    float4 rv; rv.x = rqt[0]; rv.y = rqt[1]; rv.z = rqt[2]; rv.w = rqt[3];
    *(float4*)&rql_s[wid][gp*4] = rv;
  }
  unsigned short* tqb = tq_s[wid];
#pragma unroll
  for (int r = 0; r < 4; r++){
    tqb[(gp*4+r)*32 + li]      = f2bf(tq0[r]);
    tqb[(gp*4+r)*32 + 16 + li] = f2bf(tq1[r]);
  }

  // MFMA3: S[j][i] = hk[j] . tq[i]   (uk folds in via u' inside tq)
  const bf16x8 ak = *(const bf16x8*)(hkb + li*32 + gp*8);
  const bf16x8 bt = *(const bf16x8*)(tqb + li*32 + gp*8);
  f32x4 zz = {0.f,0.f,0.f,0.f};
  f32x4 S = __builtin_amdgcn_mfma_f32_16x16x32_bf16(ak, bt, zz, 0, 0, 0);
  const float rc = rql_s[wid][li];
  float s0 = S[0]+rc, s1 = S[1]+rc, s2 = S[2]+rc, s3 = S[3]+rc;

  // softmax over senders j (4 regs x 4 lane-groups)
  float mx = fmaxf(fmaxf(s0, s1), fmaxf(s2, s3));
  mx = fmaxf(mx, __shfl_xor(mx, 16)); mx = fmaxf(mx, __shfl_xor(mx, 32));
  float e0 = __expf(s0-mx), e1 = __expf(s1-mx), e2 = __expf(s2-mx), e3 = __expf(s3-mx);
  float sm = e0+e1+e2+e3;
  sm += __shfl_xor(sm, 16); sm += __shfl_xor(sm, 32);
  const float inv = 1.f / sm;
  const float a0 = e0*inv, a1 = e1*inv, a2 = e2*inv, a3 = e3*inv;

  // alpha out: transpose via tq_s (reused as float[256]) -> coalesced b128
  float* aT = (float*)tqb;
  { float4 av4; av4.x = a0; av4.y = a1; av4.z = a2; av4.w = a3;
    *(float4*)&aT[li*16 + gp*4] = av4; }
  { float4 o4 = *(const float4*)&aT[l*4];
    *(float4*)(out_alpha + (size_t)b*256 + l*4) = o4; }

  // ov[i] = sum_j alpha[i][j] * vv[j]
  float4 vq4 = *(const float4*)&vvl_s[wid][gp*4];
  float ovp = a0*vq4.x + a1*vq4.y + a2*vq4.z + a3*vq4.w;
  ovp += __shfl_xor(ovp, 16); ovp += __shfl_xor(ovp, 32);
  if (l < 16) ws_ov[(size_t)b*16 + l] = ovp;
}

// ---------------------------------------------------------------------------
// KC: combine. Reads nv in place from out_x, overwrites with final x.
// ---------------------------------------------------------------------------
__global__ __launch_bounds__(256) void kc_kernel(
    const float* __restrict__ policies, const float* __restrict__ actions,
    const float* __restrict__ weights, const float* __restrict__ Wval,
    const float* __restrict__ bval, const float* __restrict__ ws_ov,
    float* __restrict__ out_x)
{
  __shared__ float pv_l[16], av_l[16];
  const int b = blockIdx.x, t = threadIdx.x;
  const float w = weights[0];
  {
    const int j = t >> 4; const int a0 = (t & 15) * 2;
    const float wa = Wval[128 + a0], wb = Wval[129 + a0];
    const float* pp = policies + ((size_t)(b * 16 + j)) * 32 + a0;
    const float* ap = actions  + ((size_t)(b * 16 + j)) * 32 + a0;
    float p = pp[0]*wa + pp[1]*wb;
    float a = ap[0]*wa + ap[1]*wb;
    GRPSUM(p); GRPSUM(a);
    if ((t & 15) == 0){ pv_l[j] = p; av_l[j] = a; }
  }
  __syncthreads();
  const int j = t & 15;
  const float pv = pv_l[j], av = av_l[j];
  const float nv = out_x[(size_t)b * 256 + t];
  const float zval = w * av + (1.f - w) * pv + nv;
  float zs = zval;
  GRPSUM(zs);
  out_x[(size_t)b * 256 + t] = ws_ov[(size_t)b * 16 + j] + (pv - zval + zs) * 0.0625f + bval[0];
}

// ---------------------------------------------------------------------------
extern "C" void kernel_launch(void* const* d_in, const int* in_sizes, int n_in,
                              void* d_out, int out_size, void* d_ws, size_t ws_size,
                              hipStream_t stream)
{
  const float* obs      = (const float*)d_in[0];
  const float* policies = (const float*)d_in[1];
  const float* actions  = (const float*)d_in[2];
  const float* weights  = (const float*)d_in[3];
  const float* noise    = (const float*)d_in[4];
  const float* Wk1  = (const float*)d_in[5];
  const float* bk1  = (const float*)d_in[6];
  const float* Wk2  = (const float*)d_in[7];
  const float* bk2  = (const float*)d_in[8];
  const float* Wq1  = (const float*)d_in[9];
  const float* bq1  = (const float*)d_in[10];
  const float* Wq2  = (const float*)d_in[11];
  const float* bq2  = (const float*)d_in[12];
  const float* Wv1  = (const float*)d_in[13];
  const float* bv1  = (const float*)d_in[14];
  const float* Wv2  = (const float*)d_in[15];
  const float* bv2  = (const float*)d_in[16];
  const float* Wval = (const float*)d_in[17];
  const float* bval = (const float*)d_in[18];

  float* out = (float*)d_out;
  float* ws  = (float*)d_ws;
  float* ws_ov = ws + 7168;

  const int NODES = in_sizes[0] / 128;
  const int B = NODES / 16;
  const int BA = B / 4;

  float* out_x     = out;
  float* out_alpha = out + (size_t)NODES * 16;

  hipLaunchKernelGGL(k0_kernel, dim3(64), dim3(64), 0, stream,
                     Wk1, Wq1, Wv1, Wk2, bk2, Wq2, bq2, Wv2, bv2, Wval, ws);
  hipLaunchKernelGGL(k1_kernel, dim3(BA + B), dim3(256), 0, stream,
                     obs, noise, bk1, bq1, bv1, Wval, ws,
                     out_x, out_alpha, ws_ov, BA);
  hipLaunchKernelGGL(kc_kernel, dim3(B), dim3(256), 0, stream,
                     policies, actions, weights, Wval, bval, ws_ov, out_x);
}

// Round 4
// 30.796 us; speedup vs baseline: 1.3368x; 1.0182x over previous
//
#include <hip/hip_runtime.h>

typedef __attribute__((ext_vector_type(8))) short bf16x8;
typedef __attribute__((ext_vector_type(4))) float f32x4;

__device__ __forceinline__ unsigned short f2bf(float f){
  union { float f; unsigned int u; } v; v.f = f;
  unsigned int u = v.u;
  return (unsigned short)((u + 0x7FFFu + ((u >> 16) & 1u)) >> 16);  // RNE
}

__device__ __forceinline__ float fast_tanh(float x){
  x = fminf(15.f, fmaxf(-15.f, x));
  float e = __expf(2.f * x);
  return (e - 1.f) / (e + 1.f);
}

__device__ __forceinline__ float dot128(const float* __restrict__ a,
                                        const float* __restrict__ b){
  float s = 0.f;
  for (int c = 0; c < 128; c += 4){
    float4 x = *(const float4*)(a + c);
    float4 y = *(const float4*)(b + c);
    s += x.x*y.x + x.y*y.y + x.z*y.z + x.w*y.w;
  }
  return s;
}

#define GRPSUM(x) { x += __shfl_xor(x, 1); x += __shfl_xor(x, 2); \
                    x += __shfl_xor(x, 4); x += __shfl_xor(x, 8); }

// ---------------------------------------------------------------------------
// ws float layout:
//   f[0 .. 6144)    : Bpack   — MFMA1 B-frags (12288 bf16), layer-1 weights
//   f[6144 .. 6912) : B2pack  — MFMA2' B-frags (1536 bf16): 3 tiles
//   f[6912 .. 6944) : u'[h] = rs*(Wk2[h].bq2)
//   f[6944 .. 6976) : wv[h] = Wv2[h].Wval[0:128]
//   f[6976] = rs*(bk2.bq2)   f[6977] = bv2.Wval[0:128]
// ---------------------------------------------------------------------------
__global__ __launch_bounds__(64) void k0_kernel(
    const float* __restrict__ Wk1, const float* __restrict__ Wq1, const float* __restrict__ Wv1,
    const float* __restrict__ Wk2, const float* __restrict__ bk2,
    const float* __restrict__ Wq2, const float* __restrict__ bq2,
    const float* __restrict__ Wv2, const float* __restrict__ bv2,
    const float* __restrict__ Wval, float* __restrict__ ws)
{
  const int tid = blockIdx.x * 64 + threadIdx.x;  // 0..4095
  const float rs = 0.08838834764831845f;          // 1/sqrt(128)
  unsigned short* bp = (unsigned short*)ws;
  unsigned short* b2 = (unsigned short*)(ws + 6144);

  if (tid < 1536){
    const int e = tid & 7, l = (tid >> 3) & 63, tt = tid >> 9;
    const int g = (l >> 4) * 8 + e;
    float val = 0.f;
    if (tt < 2){
      const int h = (l & 15) + tt * 16;
      val = rs * dot128(Wk2 + h * 128, Wq2 + g * 128);
    } else if ((l & 15) == 0){
      val = rs * dot128(Wq2 + g * 128, bk2);
    }
    b2[tid] = f2bf(val);
  } else if (tid < 1600){
    const int h = tid - 1536;
    if (h < 32) ws[6912 + h] = rs * dot128(Wk2 + h * 128, bq2);
    else        ws[6944 + (h - 32)] = dot128(Wv2 + (h - 32) * 128, Wval);
  } else if (tid == 1600){
    ws[6976] = rs * dot128(bk2, bq2);
  } else if (tid == 1601){
    ws[6977] = dot128(bv2, Wval);
  }

  for (int idx = tid; idx < 12288; idx += 4096){
    const int e  = idx & 7;
    const int l  = (idx >> 3) & 63;
    const int kc = (idx >> 9) & 3;
    const int nt = (idx >> 11) & 1;
    const int m  = idx >> 12;
    const float* W1 = (m == 0) ? Wk1 : ((m == 1) ? Wq1 : Wv1);
    const int krow = kc * 32 + (l >> 4) * 8 + e;
    const int col  = nt * 16 + (l & 15);
    bp[idx] = f2bf(W1[krow * 32 + col]);
  }
}

// ---------------------------------------------------------------------------
// Fused: one wave = one batch, end to end. MFMA score path (r3, validated),
// noise double-buffered in registers, final combine in-wave. No barriers.
// ---------------------------------------------------------------------------
__global__ __launch_bounds__(256, 2) void fused_kernel(
    const float* __restrict__ obs,
    const float* __restrict__ policies, const float* __restrict__ actions,
    const float* __restrict__ noise, const float* __restrict__ weights,
    const float* __restrict__ bk1p, const float* __restrict__ bq1p, const float* __restrict__ bv1p,
    const float* __restrict__ Wval, const float* __restrict__ bval,
    const float* __restrict__ ws,
    float* __restrict__ out_x, float* __restrict__ out_alpha)
{
  __shared__ __align__(16) unsigned short hk_s[4][512];
  __shared__ __align__(16) unsigned short hq_s[4][512];
  __shared__ __align__(16) unsigned short tq_s[4][512];
  __shared__ __align__(16) float rql_s[4][16];
  __shared__ __align__(16) float vvl_s[4][16];
  __shared__ __align__(16) float nvw_s[4][256];
  __shared__ __align__(16) float pvl_s[4][16], avl_s[4][16], ovl_s[4][16];

  const int t = threadIdx.x;
  const int wid = t >> 6, l = t & 63;
  const int b = blockIdx.x * 4 + wid;
  const int li = l & 15, gp = l >> 4;

  // ---- issue obs loads (needed first: MFMA1)
  const float* orow = obs + (size_t)(b * 16 + li) * 128 + gp * 8;
  float4 ob[8];
#pragma unroll
  for (int kc = 0; kc < 4; kc++){
    ob[kc * 2]     = *(const float4*)(orow + kc * 32);
    ob[kc * 2 + 1] = *(const float4*)(orow + kc * 32 + 4);
  }

  // ---- issue noise chunk 0 (rows 0..63)
  const int q8 = l & 7, r8 = l >> 3;
  const float* nb = noise + (size_t)b * 8192 + r8 * 32 + q8 * 4;
  float4 nzA[8], nzB[8];
#pragma unroll
  for (int p = 0; p < 8; p++) nzA[p] = *(const float4*)(nb + p * 256);

  // ---- issue pol/act loads
  const int jp = l >> 2, seg = l & 3;
  const float* pp = policies + (size_t)(b * 16 + jp) * 32 + seg * 8;
  const float* ap = actions  + (size_t)(b * 16 + jp) * 32 + seg * 8;
  float4 pA0 = *(const float4*)(pp);
  float4 pA1 = *(const float4*)(pp + 4);
  float4 aA0 = *(const float4*)(ap);
  float4 aA1 = *(const float4*)(ap + 4);
  const float4 wpa = *(const float4*)(Wval + 128 + seg * 8);
  const float4 wpb = *(const float4*)(Wval + 132 + seg * 8);
  const float4 wv4 = *(const float4*)(Wval + 128 + q8 * 4);

  // ---- tables (uniform -> scalar loads) + per-lane B2 frags
  const bf16x8* bp  = (const bf16x8*)ws;
  const bf16x8* b2p = (const bf16x8*)(ws + 6144);
  const bf16x8 b20 = b2p[l], b21 = b2p[64 + l], b22 = b2p[128 + l];
  const float u0 = ws[6912 + li], u1 = ws[6928 + li];
  const float wv0 = ws[6944 + li], wv1 = ws[6960 + li];
  const float ccv = ws[6976], cvv = ws[6977];
  const float bk0 = bk1p[li], bk1v = bk1p[16 + li];
  const float bq0 = bq1p[li], bq1v = bq1p[16 + li];
  const float bv0 = bv1p[li], bv1v = bv1p[16 + li];
  const float wscal = weights[0];
  const float bvs = bval[0];

  // ---- A frags + MFMA1: h = obs @ W1 for k,q,v (6 tiles x K=128)
  bf16x8 afr[4];
#pragma unroll
  for (int kc = 0; kc < 4; kc++){
    bf16x8 a;
    a[0]=(short)f2bf(ob[kc*2].x); a[1]=(short)f2bf(ob[kc*2].y);
    a[2]=(short)f2bf(ob[kc*2].z); a[3]=(short)f2bf(ob[kc*2].w);
    a[4]=(short)f2bf(ob[kc*2+1].x); a[5]=(short)f2bf(ob[kc*2+1].y);
    a[6]=(short)f2bf(ob[kc*2+1].z); a[7]=(short)f2bf(ob[kc*2+1].w);
    afr[kc] = a;
  }
  f32x4 acc[6];
#pragma unroll
  for (int mt = 0; mt < 6; mt++){ f32x4 z = {0.f,0.f,0.f,0.f}; acc[mt] = z; }
#pragma unroll
  for (int mt = 0; mt < 6; mt++){
#pragma unroll
    for (int kc = 0; kc < 4; kc++)
      acc[mt] = __builtin_amdgcn_mfma_f32_16x16x32_bf16(afr[kc], bp[(mt*4+kc)*64 + l], acc[mt], 0, 0, 0);
  }

  // ---- tanh + pack hk, hq into [node][h] bf16 LDS images (per-wave)
  unsigned short* hkb = hk_s[wid];
  unsigned short* hqb = hq_s[wid];
#pragma unroll
  for (int tile = 0; tile < 2; tile++){
    const float bk_ = tile ? bk1v : bk0;
    const float bq_ = tile ? bq1v : bq0;
    f32x4 ck = acc[tile], cq = acc[2 + tile];
#pragma unroll
    for (int r = 0; r < 4; r++){
      hkb[(gp*4+r)*32 + tile*16 + li] = f2bf(fast_tanh(ck[r] + bk_));
      hqb[(gp*4+r)*32 + tile*16 + li] = f2bf(fast_tanh(cq[r] + bq_));
    }
  }

  // ---- vv[j] = wv . tanh(h_v[j]) + cv
  {
    f32x4 c0 = acc[4], c1 = acc[5];
    float vp0 = wv0*fast_tanh(c0[0]+bv0) + wv1*fast_tanh(c1[0]+bv1v);
    float vp1 = wv0*fast_tanh(c0[1]+bv0) + wv1*fast_tanh(c1[1]+bv1v);
    float vp2 = wv0*fast_tanh(c0[2]+bv0) + wv1*fast_tanh(c1[2]+bv1v);
    float vp3 = wv0*fast_tanh(c0[3]+bv0) + wv1*fast_tanh(c1[3]+bv1v);
    GRPSUM(vp0); GRPSUM(vp1); GRPSUM(vp2); GRPSUM(vp3);
    if (li == 0){
      float4 vq; vq.x = vp0+cvv; vq.y = vp1+cvv; vq.z = vp2+cvv; vq.w = vp3+cvv;
      *(float4*)&vvl_s[wid][gp*4] = vq;
    }
  }

  // ---- issue noise chunk 1, then consume chunk 0 (rows 0..63)
#pragma unroll
  for (int p = 0; p < 8; p++) nzB[p] = *(const float4*)(nb + 2048 + p * 256);
  float* nvw = nvw_s[wid];
#pragma unroll
  for (int p = 0; p < 8; p++){
    float s = nzA[p].x*wv4.x + nzA[p].y*wv4.y + nzA[p].z*wv4.z + nzA[p].w*wv4.w;
    s += __shfl_xor(s, 1); s += __shfl_xor(s, 2); s += __shfl_xor(s, 4);
    if (q8 == 0) nvw[p * 8 + r8] = s;
  }
  // ---- issue chunk 2
#pragma unroll
  for (int p = 0; p < 8; p++) nzA[p] = *(const float4*)(nb + 4096 + p * 256);

  // ---- MFMA2': tq[i][h] = hq[i].(rs*M^T)[.,h] + rs*u[h]; tile2 -> rq[i]+cc
  const bf16x8 aq = *(const bf16x8*)(hqb + li*32 + gp*8);
  f32x4 cu0 = {u0,u0,u0,u0}, cu1 = {u1,u1,u1,u1}, cu2 = {ccv,ccv,ccv,ccv};
  f32x4 tq0 = __builtin_amdgcn_mfma_f32_16x16x32_bf16(aq, b20, cu0, 0, 0, 0);
  f32x4 tq1 = __builtin_amdgcn_mfma_f32_16x16x32_bf16(aq, b21, cu1, 0, 0, 0);
  f32x4 rqt = __builtin_amdgcn_mfma_f32_16x16x32_bf16(aq, b22, cu2, 0, 0, 0);
  if (li == 0){
    float4 rv; rv.x = rqt[0]; rv.y = rqt[1]; rv.z = rqt[2]; rv.w = rqt[3];
    *(float4*)&rql_s[wid][gp*4] = rv;
  }
  unsigned short* tqb = tq_s[wid];
#pragma unroll
  for (int r = 0; r < 4; r++){
    tqb[(gp*4+r)*32 + li]      = f2bf(tq0[r]);
    tqb[(gp*4+r)*32 + 16 + li] = f2bf(tq1[r]);
  }

  // ---- MFMA3: S[j][i] = hk[j] . tq[i]
  const bf16x8 ak = *(const bf16x8*)(hkb + li*32 + gp*8);
  const bf16x8 bt = *(const bf16x8*)(tqb + li*32 + gp*8);
  f32x4 zz = {0.f,0.f,0.f,0.f};
  f32x4 S = __builtin_amdgcn_mfma_f32_16x16x32_bf16(ak, bt, zz, 0, 0, 0);
  const float rc = rql_s[wid][li];
  float s0 = S[0]+rc, s1 = S[1]+rc, s2 = S[2]+rc, s3 = S[3]+rc;

  // ---- softmax over senders j (4 regs x 4 lane-groups)
  float mx = fmaxf(fmaxf(s0, s1), fmaxf(s2, s3));
  mx = fmaxf(mx, __shfl_xor(mx, 16)); mx = fmaxf(mx, __shfl_xor(mx, 32));
  float e0 = __expf(s0-mx), e1 = __expf(s1-mx), e2 = __expf(s2-mx), e3 = __expf(s3-mx);
  float sm = e0+e1+e2+e3;
  sm += __shfl_xor(sm, 16); sm += __shfl_xor(sm, 32);
  const float inv = 1.f / sm;
  const float a0 = e0*inv, a1 = e1*inv, a2 = e2*inv, a3 = e3*inv;

  // ---- alpha out: transpose via tq_s (reused as float[256]) -> coalesced
  float* aT = (float*)tqb;
  { float4 av4; av4.x = a0; av4.y = a1; av4.z = a2; av4.w = a3;
    *(float4*)&aT[li*16 + gp*4] = av4; }
  { float4 o4 = *(const float4*)&aT[l*4];
    *(float4*)(out_alpha + (size_t)b*256 + l*4) = o4; }

  // ---- ov[i] = sum_j alpha[i][j] * vv[j]  -> LDS
  float4 vq4 = *(const float4*)&vvl_s[wid][gp*4];
  float ovp = a0*vq4.x + a1*vq4.y + a2*vq4.z + a3*vq4.w;
  ovp += __shfl_xor(ovp, 16); ovp += __shfl_xor(ovp, 32);
  if (l < 16) ovl_s[wid][li] = ovp;

  // ---- consume chunk 1 (rows 64..127), issue chunk 3
#pragma unroll
  for (int p = 0; p < 8; p++){
    float s = nzB[p].x*wv4.x + nzB[p].y*wv4.y + nzB[p].z*wv4.z + nzB[p].w*wv4.w;
    s += __shfl_xor(s, 1); s += __shfl_xor(s, 2); s += __shfl_xor(s, 4);
    if (q8 == 0) nvw[64 + p * 8 + r8] = s;
  }
#pragma unroll
  for (int p = 0; p < 8; p++) nzB[p] = *(const float4*)(nb + 6144 + p * 256);

  // ---- pv/av: 4 lanes per node jp, reduce over seg
  {
    float pvv = pA0.x*wpa.x + pA0.y*wpa.y + pA0.z*wpa.z + pA0.w*wpa.w
              + pA1.x*wpb.x + pA1.y*wpb.y + pA1.z*wpb.z + pA1.w*wpb.w;
    float avv = aA0.x*wpa.x + aA0.y*wpa.y + aA0.z*wpa.z + aA0.w*wpa.w
              + aA1.x*wpb.x + aA1.y*wpb.y + aA1.z*wpb.z + aA1.w*wpb.w;
    pvv += __shfl_xor(pvv, 1); pvv += __shfl_xor(pvv, 2);
    avv += __shfl_xor(avv, 1); avv += __shfl_xor(avv, 2);
    if (seg == 0){ pvl_s[wid][jp] = pvv; avl_s[wid][jp] = avv; }
  }

  // ---- consume chunk 2 (rows 128..191), chunk 3 (rows 192..255)
#pragma unroll
  for (int p = 0; p < 8; p++){
    float s = nzA[p].x*wv4.x + nzA[p].y*wv4.y + nzA[p].z*wv4.z + nzA[p].w*wv4.w;
    s += __shfl_xor(s, 1); s += __shfl_xor(s, 2); s += __shfl_xor(s, 4);
    if (q8 == 0) nvw[128 + p * 8 + r8] = s;
  }
#pragma unroll
  for (int p = 0; p < 8; p++){
    float s = nzB[p].x*wv4.x + nzB[p].y*wv4.y + nzB[p].z*wv4.z + nzB[p].w*wv4.w;
    s += __shfl_xor(s, 1); s += __shfl_xor(s, 2); s += __shfl_xor(s, 4);
    if (q8 == 0) nvw[192 + p * 8 + r8] = s;
  }

  // ---- final combine: lane covers out[i=l>>2][j=(l&3)*4 .. +3]
  {
    const int j0 = (l & 3) * 4;
    const int ii = l >> 2;
    float4 pv4 = *(const float4*)&pvl_s[wid][j0];
    float4 av4 = *(const float4*)&avl_s[wid][j0];
    float4 ov4 = *(const float4*)&ovl_s[wid][j0];
    float4 nv4 = *(const float4*)&nvw[ii * 16 + j0];
    const float om = 1.f - wscal;
    float z0 = wscal * av4.x + om * pv4.x + nv4.x;
    float z1 = wscal * av4.y + om * pv4.y + nv4.y;
    float z2 = wscal * av4.z + om * pv4.z + nv4.z;
    float z3 = wscal * av4.w + om * pv4.w + nv4.w;
    float zs = z0 + z1 + z2 + z3;
    zs += __shfl_xor(zs, 1); zs += __shfl_xor(zs, 2);
    float4 o;
    o.x = ov4.x + (pv4.x - z0 + zs) * 0.0625f + bvs;
    o.y = ov4.y + (pv4.y - z1 + zs) * 0.0625f + bvs;
    o.z = ov4.z + (pv4.z - z2 + zs) * 0.0625f + bvs;
    o.w = ov4.w + (pv4.w - z3 + zs) * 0.0625f + bvs;
    *(float4*)(out_x + (size_t)b * 256 + l * 4) = o;
  }
}

// ---------------------------------------------------------------------------
extern "C" void kernel_launch(void* const* d_in, const int* in_sizes, int n_in,
                              void* d_out, int out_size, void* d_ws, size_t ws_size,
                              hipStream_t stream)
{
  const float* obs      = (const float*)d_in[0];
  const float* policies = (const float*)d_in[1];
  const float* actions  = (const float*)d_in[2];
  const float* weights  = (const float*)d_in[3];
  const float* noise    = (const float*)d_in[4];
  const float* Wk1  = (const float*)d_in[5];
  const float* bk1  = (const float*)d_in[6];
  const float* Wk2  = (const float*)d_in[7];
  const float* bk2  = (const float*)d_in[8];
  const float* Wq1  = (const float*)d_in[9];
  const float* bq1  = (const float*)d_in[10];
  const float* Wq2  = (const float*)d_in[11];
  const float* bq2  = (const float*)d_in[12];
  const float* Wv1  = (const float*)d_in[13];
  const float* bv1  = (const float*)d_in[14];
  const float* Wv2  = (const float*)d_in[15];
  const float* bv2  = (const float*)d_in[16];
  const float* Wval = (const float*)d_in[17];
  const float* bval = (const float*)d_in[18];

  float* out = (float*)d_out;
  float* ws  = (float*)d_ws;

  const int NODES = in_sizes[0] / 128;
  const int B = NODES / 16;

  float* out_x     = out;
  float* out_alpha = out + (size_t)NODES * 16;

  hipLaunchKernelGGL(k0_kernel, dim3(64), dim3(64), 0, stream,
                     Wk1, Wq1, Wv1, Wk2, bk2, Wq2, bq2, Wv2, bv2, Wval, ws);
  hipLaunchKernelGGL(fused_kernel, dim3(B / 4), dim3(256), 0, stream,
                     obs, policies, actions, noise, weights,
                     bk1, bq1, bv1, Wval, bval, ws,
                     out_x, out_alpha);
}